// Round 7
// baseline (505.451 us; speedup 1.0000x reference)
//
#include <hip/hip_runtime.h>
#include <hip/hip_cooperative_groups.h>

namespace cg = cooperative_groups;

#define NN 50000
#define NE 150000
#define NBLK 256
#define NTHR 512
#define NG (NBLK * NTHR)
#define NB2 98            // ceil(NN/512) chunks for the coop scan
#define G2 98             // nodes per conv2 tile
#define NT2 ((NN + G2 - 1) / G2)   // 511 tiles
#define NB 196            // ceil(NN/256) for the fallback path

struct MArgs {
    const float *x, *ef, *W1, *b1, *W2, *b2, *W3, *b3;
    const float *Wv1, *bv1, *Wv2, *bv2, *Wa1, *ba1, *Wa2, *ba2;
    const int *src, *dst;
    float *out;
    int *deg_out, *deg_in, *cur_in, *bsum, *rp_in;
    float *c, *t_pad, *g_pad, *hv_pad, *ha_pad, *a_pad;
    float *dins, *douts, *v;
    float4 *xs4, *ef4, *h1s4;
    int2 *ndcsr;
    uint4 *zbase;
    int zcount;
};

// ================= cooperative mega-kernel: whole model, 10 grid syncs =================
__global__ __launch_bounds__(NTHR, 1) void k_mega(MArgs A) {
    cg::grid_group grid = cg::this_grid();
    const int tid = threadIdx.x;
    const int bid = blockIdx.x;
    const int gid = bid * NTHR + tid;

    __shared__ float smem[G2 * 12 + 2 * G2 + 16];  // reused pool (>= 512 words)

    // ---- P0: zero accumulators (replaces memset) ----
    for (int i = gid; i < A.zcount; i += NG) A.zbase[i] = make_uint4(0, 0, 0, 0);
    grid.sync();

    // ---- P1: degree histograms ----
    for (int e = gid; e < NE; e += NG) {
        atomicAdd(&A.deg_out[A.src[e]], 1);
        atomicAdd(&A.deg_in[A.dst[e]], 1);
    }
    grid.sync();

    // ---- P2: per-chunk sums of deg_in ----
    if (bid < NB2) {
        int idx = bid * NTHR + tid;
        int d = (idx < NN) ? A.deg_in[idx] : 0;
        int* si = (int*)smem;
        si[tid] = d;
        __syncthreads();
        for (int off = 256; off >= 1; off >>= 1) {
            if (tid < off) si[tid] += si[tid + off];
            __syncthreads();
        }
        if (tid == 0) A.bsum[bid] = si[0];
    }
    grid.sync();

    // ---- P3: rowptr (exclusive scan) + norm tables + prescaled x ----
    if (bid < NB2) {
        int* si = (int*)smem;
        si[tid] = (tid < bid) ? A.bsum[tid] : 0;
        __syncthreads();
        for (int off = 256; off >= 1; off >>= 1) {
            if (tid < off) si[tid] += si[tid + off];
            __syncthreads();
        }
        int off_in = si[0];
        __syncthreads();
        int idx = bid * NTHR + tid;
        int di = (idx < NN) ? A.deg_in[idx] : 0;
        si[tid] = di;
        __syncthreads();
        for (int off = 1; off < NTHR; off <<= 1) {
            int a = (tid >= off) ? si[tid - off] : 0;
            __syncthreads();
            si[tid] += a;
            __syncthreads();
        }
        if (idx < NN) {
            A.rp_in[idx] = off_in + si[tid] - di;
            float dif = rsqrtf((float)(di + 1));
            float dqf = rsqrtf((float)(A.deg_out[idx] + 1));
            A.dins[idx] = dif;
            A.douts[idx] = dqf;
            float4 x4 = ((const float4*)A.x)[idx];
            x4.x *= dqf; x4.y *= dqf; x4.z *= dqf; x4.w *= dqf;
            A.xs4[idx] = x4;
        }
        if (bid == 0 && tid == 0) A.rp_in[NN] = NE;
    }
    grid.sync();

    // ---- P4: scatter edges into dst-CSR, permute ef, accumulate c ----
    for (int e = gid; e < NE; e += NG) {
        int s = A.src[e], d = A.dst[e];
        int pi = A.rp_in[d] + atomicAdd(&A.cur_in[d], 1);
        A.ndcsr[pi] = make_int2(s, d);
        const float* er = A.ef + (size_t)e * 11;
        A.ef4[(size_t)pi * 3 + 0] = make_float4(er[0], er[1], er[2], er[3]);
        A.ef4[(size_t)pi * 3 + 1] = make_float4(er[4], er[5], er[6], er[7]);
        A.ef4[(size_t)pi * 3 + 2] = make_float4(er[8], er[9], er[10], 0.f);
        atomicAdd(&A.c[s], A.dins[d]);
    }
    grid.sync();

    // ---- P5: conv1 gather + 4->11 matvec + relu ----
    for (int n = gid; n < NN; n += NG) {
        float din = A.dins[n], dout = A.douts[n];
        float4 a = A.xs4[n];
        int beg = A.rp_in[n], end = A.rp_in[n + 1];
        for (int p = beg; p < end; p++) {
            float4 xs = A.xs4[A.ndcsr[p].x];
            a.x += xs.x; a.y += xs.y; a.z += xs.z; a.w += xs.w;
        }
        float y[12];
        #pragma unroll
        for (int j = 0; j < 11; j++) {
            float t2 = a.x * A.W1[0 * 11 + j] + a.y * A.W1[1 * 11 + j] +
                       a.z * A.W1[2 * 11 + j] + a.w * A.W1[3 * 11 + j];
            y[j] = fmaxf(fmaf(t2, din, A.b1[j]), 0.f) * dout;
        }
        y[11] = 0.f;
        A.h1s4[(size_t)n * 3 + 0] = make_float4(y[0], y[1], y[2],  y[3]);
        A.h1s4[(size_t)n * 3 + 1] = make_float4(y[4], y[5], y[6],  y[7]);
        A.h1s4[(size_t)n * 3 + 2] = make_float4(y[8], y[9], y[10], y[11]);
    }
    grid.sync();

    // ---- P6: conv2 tile gather + matvec + weighted mean-reduce into t_pad ----
    {
        float* tile   = smem;
        float* din_sh = smem + G2 * 12;
        float* w_sh   = smem + G2 * 12 + G2;
        float w[11];
        #pragma unroll
        for (int j = 0; j < 11; j++) w[j] = A.W2[j * 512 + tid];
        float bias = A.b2[tid];
        float accT = 0.f;
        for (int t2 = bid; t2 < NT2; t2 += NBLK) {
            __syncthreads();
            int n0 = t2 * G2;
            int nend = (n0 + G2 < NN) ? n0 + G2 : NN;
            for (int i = tid; i < G2 * 12; i += NTHR) tile[i] = 0.f;
            if (tid < G2) {
                int n = n0 + tid;
                if (n < NN) {
                    float din = A.dins[n];
                    din_sh[tid] = din;
                    w_sh[tid]   = (A.c[n] + din) * A.douts[n] * (1.0f / NN);
                } else { din_sh[tid] = 0.f; w_sh[tid] = 0.f; }
            }
            __syncthreads();
            int pbeg = A.rp_in[n0], pend = A.rp_in[nend];
            for (int p = pbeg + tid; p < pend; p += NTHR) {
                int2 sd = A.ndcsr[p];
                float4 ha = A.h1s4[(size_t)sd.x * 3 + 0];
                float4 hb = A.h1s4[(size_t)sd.x * 3 + 1];
                float4 hc = A.h1s4[(size_t)sd.x * 3 + 2];
                float4 ea = A.ef4[(size_t)p * 3 + 0];
                float4 eb = A.ef4[(size_t)p * 3 + 1];
                float4 ec = A.ef4[(size_t)p * 3 + 2];
                float* row = &tile[(sd.y - n0) * 12];
                atomicAdd(&row[0],  ha.x * ea.x);
                atomicAdd(&row[1],  ha.y * ea.y);
                atomicAdd(&row[2],  ha.z * ea.z);
                atomicAdd(&row[3],  ha.w * ea.w);
                atomicAdd(&row[4],  hb.x * eb.x);
                atomicAdd(&row[5],  hb.y * eb.y);
                atomicAdd(&row[6],  hb.z * eb.z);
                atomicAdd(&row[7],  hb.w * eb.w);
                atomicAdd(&row[8],  hc.x * ec.x);
                atomicAdd(&row[9],  hc.y * ec.y);
                atomicAdd(&row[10], hc.z * ec.z);
            }
            __syncthreads();
            int cnt = nend - n0;
            for (int i = 0; i < cnt; i++) {
                const float4* tr = (const float4*)&tile[i * 12];
                float4 ta = tr[0], tb = tr[1], tc = tr[2];
                float dot = ta.x * w[0] + ta.y * w[1] + ta.z * w[2] + ta.w * w[3] +
                            tb.x * w[4] + tb.y * w[5] + tb.z * w[6] + tb.w * w[7] +
                            tc.x * w[8] + tc.y * w[9] + tc.z * w[10];
                accT = fmaf(w_sh[i], fmaxf(fmaf(dot, din_sh[i], bias), 0.f), accT);
            }
        }
        atomicAdd(&A.t_pad[tid * 16], accT);
    }
    grid.sync();

    // ---- P7: g = t @ W3 + b3 (32 vblocks: oc2 x kc16, chunk 32) ----
    if (bid < 32) {
        int oc = bid & 1, kc = bid >> 1;
        int o = oc * NTHR + tid;      // 0..1023
        int k0 = kc * 32;
        float* ts = smem;
        if (tid < 32) ts[tid] = A.t_pad[(k0 + tid) * 16];
        __syncthreads();
        float acc = (kc == 0) ? A.b3[o] : 0.f;
        #pragma unroll
        for (int k = 0; k < 32; k++) acc = fmaf(ts[k], A.W3[(size_t)(k0 + k) * 1024 + o], acc);
        atomicAdd(&A.g_pad[o * 16], acc);
    }
    grid.sync();

    // ---- P8: heads layer 1 (128 vblocks: oc8 x kc16, chunk 64) ----
    if (bid < 128) {
        int oc = bid >> 4, kc = bid & 15;
        int idx = oc * NTHR + tid;    // 0..4095
        int k0 = kc * 64;
        float* gs = smem;
        if (tid < 64) gs[tid] = A.g_pad[(k0 + tid) * 16];
        __syncthreads();
        const float* W; float* outp; int o;
        if (idx < 2048) { W = A.Wv1; outp = A.hv_pad; o = idx; }
        else            { W = A.Wa1; outp = A.ha_pad; o = idx - 2048; }
        float acc = 0.f;
        #pragma unroll 8
        for (int k = 0; k < 64; k++) acc = fmaf(gs[k], W[(size_t)(k0 + k) * 2048 + o], acc);
        atomicAdd(&outp[o * 16], acc);
    }
    grid.sync();

    // ---- P9: heads layer 2 — a partials (64 vblocks) + v (1 vblock) ----
    if (bid < 64) {
        int oc = bid & 1, kc = bid >> 1;   // kc 0..31, chunk 64
        int k0 = kc * 64;
        float* hs = smem;
        if (tid < 64) hs[tid] = fmaxf(A.ha_pad[(k0 + tid) * 16] + A.ba1[k0 + tid], 0.f);
        __syncthreads();
        int o = oc * NTHR + tid;
        if (o < 1000) {
            float acc = 0.f;
            #pragma unroll 8
            for (int k = 0; k < 64; k++)
                acc = fmaf(hs[k], A.Wa2[(size_t)(k0 + k) * 1000 + o], acc);
            atomicAdd(&A.a_pad[o * 16], acc);
        }
    } else if (bid == 64) {
        float* red = smem;
        float acc = 0.f;
        for (int k = tid; k < 2048; k += NTHR)
            acc = fmaf(fmaxf(A.hv_pad[k * 16] + A.bv1[k], 0.f), A.Wv2[k], acc);
        red[tid] = acc;
        __syncthreads();
        for (int s2 = 256; s2 >= 1; s2 >>= 1) {
            if (tid < s2) red[tid] += red[tid + s2];
            __syncthreads();
        }
        if (tid == 0) A.v[0] = red[0] + A.bv2[0];
    }
    grid.sync();

    // ---- P10: out = v + (a - mean(a)) ----
    if (bid == 0) {
        float* red = smem;
        float a0 = (tid < 1000) ? A.a_pad[tid * 16] + A.ba2[tid] : 0.f;
        int i1 = tid + NTHR;
        float a1 = (i1 < 1000) ? A.a_pad[i1 * 16] + A.ba2[i1] : 0.f;
        red[tid] = a0 + a1;
        __syncthreads();
        for (int s2 = 256; s2 >= 1; s2 >>= 1) {
            if (tid < s2) red[tid] += red[tid + s2];
            __syncthreads();
        }
        float amean = red[0] * (1.0f / 1000.0f);
        float vv = A.v[0];
        if (tid < 1000) A.out[tid] = vv + a0 - amean;
        if (i1 < 1000)  A.out[i1]  = vv + a1 - amean;
    }
}

// ======================= fallback path (round-6 kernels, unchanged) =======================
__global__ __launch_bounds__(256) void k_deg(const int* __restrict__ src,
                                             const int* __restrict__ dst,
                                             int* __restrict__ deg_out,
                                             int* __restrict__ deg_in) {
    int e = blockIdx.x * 256 + threadIdx.x;
    if (e < NE) {
        atomicAdd(&deg_out[src[e]], 1);
        atomicAdd(&deg_in[dst[e]], 1);
    }
}

__global__ __launch_bounds__(256) void k_bsum(const int* __restrict__ deg_in,
                                              int* __restrict__ bsum_in) {
    __shared__ int si[256];
    int t = threadIdx.x;
    int idx = blockIdx.x * 256 + t;
    si[t] = (idx < NN) ? deg_in[idx] : 0;
    __syncthreads();
    for (int off = 128; off >= 1; off >>= 1) {
        if (t < off) si[t] += si[t + off];
        __syncthreads();
    }
    if (t == 0) bsum_in[blockIdx.x] = si[0];
}

__global__ __launch_bounds__(256) void k_rowptr(const int* __restrict__ deg_in,
                                                const int* __restrict__ deg_out,
                                                const int* __restrict__ bsum_in,
                                                const float* __restrict__ x,
                                                int* __restrict__ rp_in,
                                                float* __restrict__ dins,
                                                float* __restrict__ douts,
                                                float4* __restrict__ xs4) {
    __shared__ int si[256];
    int b = blockIdx.x, t = threadIdx.x;
    si[t] = (t < b) ? bsum_in[t] : 0;
    __syncthreads();
    for (int off = 128; off >= 1; off >>= 1) {
        if (t < off) si[t] += si[t + off];
        __syncthreads();
    }
    int off_in = si[0];
    __syncthreads();
    int idx = b * 256 + t;
    int di = (idx < NN) ? deg_in[idx] : 0;
    si[t] = di;
    __syncthreads();
    for (int off = 1; off < 256; off <<= 1) {
        int a = (t >= off) ? si[t - off] : 0;
        __syncthreads();
        si[t] += a;
        __syncthreads();
    }
    if (idx < NN) {
        rp_in[idx] = off_in + si[t] - di;
        float dif = rsqrtf((float)(di + 1));
        float dqf = rsqrtf((float)(deg_out[idx] + 1));
        dins[idx] = dif;
        douts[idx] = dqf;
        float4 x4 = ((const float4*)x)[idx];
        x4.x *= dqf; x4.y *= dqf; x4.z *= dqf; x4.w *= dqf;
        xs4[idx] = x4;
    }
    if (b == 0 && t == 0) rp_in[NN] = NE;
}

__global__ __launch_bounds__(256) void k_scatter(const int* __restrict__ src,
                                                 const int* __restrict__ dst,
                                                 const float* __restrict__ ef,
                                                 const int* __restrict__ rp_in,
                                                 const float* __restrict__ dins,
                                                 int* __restrict__ cur_in,
                                                 int2* __restrict__ ndcsr,
                                                 float4* __restrict__ ef4,
                                                 float* __restrict__ c) {
    int e = blockIdx.x * 256 + threadIdx.x;
    if (e >= NE) return;
    int s = src[e], d = dst[e];
    int pi = rp_in[d] + atomicAdd(&cur_in[d], 1);
    ndcsr[pi] = make_int2(s, d);
    const float* er = ef + (size_t)e * 11;
    ef4[(size_t)pi * 3 + 0] = make_float4(er[0], er[1], er[2], er[3]);
    ef4[(size_t)pi * 3 + 1] = make_float4(er[4], er[5], er[6], er[7]);
    ef4[(size_t)pi * 3 + 2] = make_float4(er[8], er[9], er[10], 0.f);
    atomicAdd(&c[s], dins[d]);
}

__global__ __launch_bounds__(256) void k_conv1g(const float4* __restrict__ xs4,
                                                const int2* __restrict__ ndcsr,
                                                const int* __restrict__ rp_in,
                                                const float* __restrict__ dins,
                                                const float* __restrict__ douts,
                                                const float* __restrict__ W1,
                                                const float* __restrict__ b1,
                                                float4* __restrict__ h1s4) {
    int n = blockIdx.x * 256 + threadIdx.x;
    if (n >= NN) return;
    float din  = dins[n];
    float dout = douts[n];
    float4 a = xs4[n];
    int beg = rp_in[n], end = rp_in[n + 1];
    for (int p = beg; p < end; p++) {
        float4 xs = xs4[ndcsr[p].x];
        a.x += xs.x; a.y += xs.y; a.z += xs.z; a.w += xs.w;
    }
    float y[12];
    #pragma unroll
    for (int j = 0; j < 11; j++) {
        float t2 = a.x * W1[0 * 11 + j] + a.y * W1[1 * 11 + j] +
                   a.z * W1[2 * 11 + j] + a.w * W1[3 * 11 + j];
        y[j] = fmaxf(fmaf(t2, din, b1[j]), 0.f) * dout;
    }
    y[11] = 0.f;
    h1s4[(size_t)n * 3 + 0] = make_float4(y[0], y[1], y[2],  y[3]);
    h1s4[(size_t)n * 3 + 1] = make_float4(y[4], y[5], y[6],  y[7]);
    h1s4[(size_t)n * 3 + 2] = make_float4(y[8], y[9], y[10], y[11]);
}

__global__ __launch_bounds__(256) void k_conv2f(const float4* __restrict__ h1s4,
                                                const float4* __restrict__ ef4,
                                                const int2* __restrict__ ndcsr,
                                                const int* __restrict__ rp_in,
                                                const float* __restrict__ c,
                                                const float* __restrict__ dins,
                                                const float* __restrict__ douts,
                                                const float* __restrict__ W2,
                                                const float* __restrict__ b2,
                                                float* __restrict__ t_pad) {
    __shared__ float tile[G2 * 12];
    __shared__ float din_sh[G2], w_sh[G2];
    int tid = threadIdx.x;
    int n0 = blockIdx.x * G2;
    int nend = (n0 + G2 < NN) ? n0 + G2 : NN;
    for (int i = tid; i < G2 * 12; i += 256) tile[i] = 0.f;
    if (tid < G2) {
        int n = n0 + tid;
        if (n < NN) {
            float din = dins[n];
            din_sh[tid] = din;
            w_sh[tid]   = (c[n] + din) * douts[n] * (1.0f / NN);
        } else { din_sh[tid] = 0.f; w_sh[tid] = 0.f; }
    }
    __syncthreads();
    int pbeg = rp_in[n0], pend = rp_in[nend];
    for (int p = pbeg + tid; p < pend; p += 256) {
        int2 sd = ndcsr[p];
        float4 ha = h1s4[(size_t)sd.x * 3 + 0];
        float4 hb = h1s4[(size_t)sd.x * 3 + 1];
        float4 hc = h1s4[(size_t)sd.x * 3 + 2];
        float4 ea = ef4[(size_t)p * 3 + 0];
        float4 eb = ef4[(size_t)p * 3 + 1];
        float4 ec = ef4[(size_t)p * 3 + 2];
        float* row = &tile[(sd.y - n0) * 12];
        atomicAdd(&row[0],  ha.x * ea.x);
        atomicAdd(&row[1],  ha.y * ea.y);
        atomicAdd(&row[2],  ha.z * ea.z);
        atomicAdd(&row[3],  ha.w * ea.w);
        atomicAdd(&row[4],  hb.x * eb.x);
        atomicAdd(&row[5],  hb.y * eb.y);
        atomicAdd(&row[6],  hb.z * eb.z);
        atomicAdd(&row[7],  hb.w * eb.w);
        atomicAdd(&row[8],  hc.x * ec.x);
        atomicAdd(&row[9],  hc.y * ec.y);
        atomicAdd(&row[10], hc.z * ec.z);
    }
    __syncthreads();
    int ch0 = tid, ch1 = tid + 256;
    float w0[11], w1[11];
    #pragma unroll
    for (int j = 0; j < 11; j++) { w0[j] = W2[j * 512 + ch0]; w1[j] = W2[j * 512 + ch1]; }
    float b0 = b2[ch0], b1v = b2[ch1];
    float acc0 = 0.f, acc1 = 0.f;
    int cnt = nend - n0;
    for (int i = 0; i < cnt; i++) {
        const float4* trow = (const float4*)&tile[i * 12];
        float4 ta = trow[0], tb = trow[1], tc = trow[2];
        float din = din_sh[i], wn = w_sh[i];
        float dot0 = ta.x * w0[0] + ta.y * w0[1] + ta.z * w0[2] + ta.w * w0[3] +
                     tb.x * w0[4] + tb.y * w0[5] + tb.z * w0[6] + tb.w * w0[7] +
                     tc.x * w0[8] + tc.y * w0[9] + tc.z * w0[10];
        float dot1 = ta.x * w1[0] + ta.y * w1[1] + ta.z * w1[2] + ta.w * w1[3] +
                     tb.x * w1[4] + tb.y * w1[5] + tb.z * w1[6] + tb.w * w1[7] +
                     tc.x * w1[8] + tc.y * w1[9] + tc.z * w1[10];
        acc0 = fmaf(wn, fmaxf(fmaf(dot0, din, b0),  0.f), acc0);
        acc1 = fmaf(wn, fmaxf(fmaf(dot1, din, b1v), 0.f), acc1);
    }
    atomicAdd(&t_pad[ch0 * 16], acc0);
    atomicAdd(&t_pad[ch1 * 16], acc1);
}

__global__ __launch_bounds__(256) void k_g(const float* __restrict__ t_pad,
                                           const float* __restrict__ W3,
                                           const float* __restrict__ b3,
                                           float* __restrict__ g_pad) {
    int b = blockIdx.x;
    int oc = b & 3, kc = b >> 2;
    int o = oc * 256 + threadIdx.x;
    int k0 = kc * 16;
    __shared__ float ts[16];
    if (threadIdx.x < 16) ts[threadIdx.x] = t_pad[(k0 + threadIdx.x) * 16];
    __syncthreads();
    float acc = (kc == 0) ? b3[o] : 0.f;
    #pragma unroll
    for (int k = 0; k < 16; k++) acc = fmaf(ts[k], W3[(size_t)(k0 + k) * 1024 + o], acc);
    atomicAdd(&g_pad[o * 16], acc);
}

__global__ __launch_bounds__(256) void k_heads1(const float* __restrict__ g_pad,
                                                const float* __restrict__ Wv1,
                                                const float* __restrict__ Wa1,
                                                float* __restrict__ hv_pad,
                                                float* __restrict__ ha_pad) {
    int b = blockIdx.x;
    int oc = b >> 5, kc = b & 31;
    int idx = oc * 256 + threadIdx.x;
    int k0 = kc * 32;
    __shared__ float gs[32];
    if (threadIdx.x < 32) gs[threadIdx.x] = g_pad[(k0 + threadIdx.x) * 16];
    __syncthreads();
    const float* W; float* outp; int o;
    if (idx < 2048) { W = Wv1; outp = hv_pad; o = idx; }
    else            { W = Wa1; outp = ha_pad; o = idx - 2048; }
    float acc = 0.f;
    #pragma unroll 8
    for (int k = 0; k < 32; k++) acc = fmaf(gs[k], W[(size_t)(k0 + k) * 2048 + o], acc);
    atomicAdd(&outp[o * 16], acc);
}

__global__ __launch_bounds__(256) void k_heads2(const float* __restrict__ hv_pad,
                                                const float* __restrict__ bv1,
                                                const float* __restrict__ ha_pad,
                                                const float* __restrict__ ba1,
                                                const float* __restrict__ Wv2,
                                                const float* __restrict__ bv2,
                                                const float* __restrict__ Wa2,
                                                float* __restrict__ a_pad,
                                                float* __restrict__ v) {
    int b = blockIdx.x;
    int tid = threadIdx.x;
    if (b < 256) {
        int oc = b >> 6, kc = b & 63;
        int k0 = kc * 32;
        __shared__ float hs[32];
        if (tid < 32) hs[tid] = fmaxf(ha_pad[(k0 + tid) * 16] + ba1[k0 + tid], 0.f);
        __syncthreads();
        int o = oc * 256 + tid;
        if (o < 1000) {
            float acc = 0.f;
            #pragma unroll 8
            for (int k = 0; k < 32; k++)
                acc = fmaf(hs[k], Wa2[(size_t)(k0 + k) * 1000 + o], acc);
            atomicAdd(&a_pad[o * 16], acc);
        }
    } else {
        __shared__ float red[256];
        float acc = 0.f;
        for (int k = tid; k < 2048; k += 256)
            acc = fmaf(fmaxf(hv_pad[k * 16] + bv1[k], 0.f), Wv2[k], acc);
        red[tid] = acc;
        __syncthreads();
        for (int s = 128; s >= 1; s >>= 1) {
            if (tid < s) red[tid] += red[tid + s];
            __syncthreads();
        }
        if (tid == 0) *v = red[0] + bv2[0];
    }
}

__global__ __launch_bounds__(1024) void k_final(const float* __restrict__ a_pad,
                                                const float* __restrict__ ba2,
                                                const float* __restrict__ vptr,
                                                float* __restrict__ out) {
    __shared__ float red[1024];
    int tid = threadIdx.x;
    float ai = (tid < 1000) ? a_pad[tid * 16] + ba2[tid] : 0.f;
    red[tid] = ai;
    __syncthreads();
    for (int s = 512; s >= 1; s >>= 1) {
        if (tid < s) red[tid] += red[tid + s];
        __syncthreads();
    }
    float amean = red[0] * (1.0f / 1000.0f);
    if (tid < 1000) out[tid] = vptr[0] + ai - amean;
}

extern "C" void kernel_launch(void* const* d_in, const int* in_sizes, int n_in,
                              void* d_out, int out_size, void* d_ws, size_t ws_size,
                              hipStream_t stream) {
    const float* x   = (const float*)d_in[0];
    const float* ef  = (const float*)d_in[1];
    const float* W1  = (const float*)d_in[2];
    const float* b1  = (const float*)d_in[3];
    const float* W2  = (const float*)d_in[4];
    const float* b2  = (const float*)d_in[5];
    const float* W3  = (const float*)d_in[6];
    const float* b3  = (const float*)d_in[7];
    const float* Wv1 = (const float*)d_in[8];
    const float* bv1 = (const float*)d_in[9];
    const float* Wv2 = (const float*)d_in[10];
    const float* bv2 = (const float*)d_in[11];
    const float* Wa1 = (const float*)d_in[12];
    const float* ba1 = (const float*)d_in[13];
    const float* Wa2 = (const float*)d_in[14];
    const float* ba2 = (const float*)d_in[15];
    const int*   src = (const int*)d_in[16];
    const int*   dst = (const int*)d_in[17];
    float* out = (float*)d_out;

    char* ws = (char*)d_ws;
    size_t off = 0;
    auto alloc = [&](size_t bytes) -> void* {
        void* p = ws + off;
        off = (off + bytes + 255) & ~(size_t)255;
        return p;
    };
    // --- zeroed region (accumulators) ---
    int*   deg_out = (int*)  alloc(NN * 4);
    int*   deg_in  = (int*)  alloc(NN * 4);
    int*   cur_in  = (int*)  alloc(NN * 4);
    float* c       = (float*)alloc(NN * 4);
    float* t_pad   = (float*)alloc(512 * 16 * 4);
    float* g_pad   = (float*)alloc(1024 * 16 * 4);
    float* hv_pad  = (float*)alloc(2048 * 16 * 4);
    float* ha_pad  = (float*)alloc(2048 * 16 * 4);
    float* a_pad   = (float*)alloc(1024 * 16 * 4);
    size_t zero_bytes = off;
    // --- non-zeroed scratch ---
    int*    bsum     = (int*)   alloc(NB * 4);   // 196 entries covers both paths
    int*    rp_in    = (int*)   alloc((NN + 1) * 4);
    float*  dins     = (float*) alloc(NN * 4);
    float*  douts    = (float*) alloc(NN * 4);
    float4* xs4      = (float4*)alloc((size_t)NN * 16);
    int2*   ndcsr    = (int2*)  alloc((size_t)NE * 8);
    float4* ef4      = (float4*)alloc((size_t)NE * 48);
    float4* h1s4     = (float4*)alloc((size_t)NN * 48);
    float*  v        = (float*) alloc(256);

    MArgs A;
    A.x = x; A.ef = ef; A.W1 = W1; A.b1 = b1; A.W2 = W2; A.b2 = b2; A.W3 = W3; A.b3 = b3;
    A.Wv1 = Wv1; A.bv1 = bv1; A.Wv2 = Wv2; A.bv2 = bv2;
    A.Wa1 = Wa1; A.ba1 = ba1; A.Wa2 = Wa2; A.ba2 = ba2;
    A.src = src; A.dst = dst; A.out = out;
    A.deg_out = deg_out; A.deg_in = deg_in; A.cur_in = cur_in; A.bsum = bsum; A.rp_in = rp_in;
    A.c = c; A.t_pad = t_pad; A.g_pad = g_pad; A.hv_pad = hv_pad; A.ha_pad = ha_pad; A.a_pad = a_pad;
    A.dins = dins; A.douts = douts; A.v = v;
    A.xs4 = xs4; A.ef4 = ef4; A.h1s4 = h1s4; A.ndcsr = ndcsr;
    A.zbase = (uint4*)d_ws; A.zcount = (int)(zero_bytes / 16);

    void* kargs[] = { &A };
    hipError_t err = hipLaunchCooperativeKernel((void*)k_mega, dim3(NBLK), dim3(NTHR),
                                                kargs, 0, stream);
    if (err != hipSuccess) {
        // -------- fallback: round-6 multi-kernel path --------
        hipMemsetAsync(d_ws, 0, zero_bytes, stream);
        k_deg<<<(NE + 255) / 256, 256, 0, stream>>>(src, dst, deg_out, deg_in);
        k_bsum<<<NB, 256, 0, stream>>>(deg_in, bsum);
        k_rowptr<<<NB, 256, 0, stream>>>(deg_in, deg_out, bsum, x, rp_in, dins, douts, xs4);
        k_scatter<<<(NE + 255) / 256, 256, 0, stream>>>(src, dst, ef, rp_in, dins,
                                                        cur_in, ndcsr, ef4, c);
        k_conv1g<<<(NN + 255) / 256, 256, 0, stream>>>(xs4, ndcsr, rp_in, dins, douts,
                                                       W1, b1, h1s4);
        k_conv2f<<<NT2, 256, 0, stream>>>(h1s4, ef4, ndcsr, rp_in, c,
                                          dins, douts, W2, b2, t_pad);
        k_g<<<128, 256, 0, stream>>>(t_pad, W3, b3, g_pad);
        k_heads1<<<512, 256, 0, stream>>>(g_pad, Wv1, Wa1, hv_pad, ha_pad);
        k_heads2<<<257, 256, 0, stream>>>(hv_pad, bv1, ha_pad, ba1, Wv2, bv2, Wa2, a_pad, v);
        k_final<<<1, 1024, 0, stream>>>(a_pad, ba2, v, out);
    }
}

// Round 8
// 212.218 us; speedup vs baseline: 2.3818x; 2.3818x over previous
//
#include <hip/hip_runtime.h>

#define NN 50000
#define NE 150000
#define NB 196   // ceil(NN/256)
#define G2 196   // nodes per conv2 tile
#define NT2 ((NN + G2 - 1) / G2)   // 256 tiles

// ---------- K1: degree histograms (self-loop handled as +1 at read) ----------
__global__ __launch_bounds__(256) void k_deg(const int* __restrict__ src,
                                             const int* __restrict__ dst,
                                             int* __restrict__ deg_out,
                                             int* __restrict__ deg_in) {
    int e = blockIdx.x * 256 + threadIdx.x;
    if (e < NE) {
        atomicAdd(&deg_out[src[e]], 1);
        atomicAdd(&deg_in[dst[e]], 1);
    }
}

// ---------- K2a: per-block partial sums of deg_in ----------
__global__ __launch_bounds__(256) void k_bsum(const int* __restrict__ deg_in,
                                              int* __restrict__ bsum_in) {
    __shared__ int si[256];
    int t = threadIdx.x;
    int idx = blockIdx.x * 256 + t;
    si[t] = (idx < NN) ? deg_in[idx] : 0;
    __syncthreads();
    for (int off = 128; off >= 1; off >>= 1) {
        if (t < off) si[t] += si[t + off];
        __syncthreads();
    }
    if (t == 0) bsum_in[blockIdx.x] = si[0];
}

// ---------- K2b: rowptr (in) + precomputed norm tables + prescaled x ----------
__global__ __launch_bounds__(256) void k_rowptr(const int* __restrict__ deg_in,
                                                const int* __restrict__ deg_out,
                                                const int* __restrict__ bsum_in,
                                                const float* __restrict__ x,
                                                int* __restrict__ rp_in,
                                                float* __restrict__ dins,
                                                float* __restrict__ douts,
                                                float4* __restrict__ xs4) {
    __shared__ int si[256];
    int b = blockIdx.x, t = threadIdx.x;
    si[t] = (t < b) ? bsum_in[t] : 0;
    __syncthreads();
    for (int off = 128; off >= 1; off >>= 1) {
        if (t < off) si[t] += si[t + off];
        __syncthreads();
    }
    int off_in = si[0];
    __syncthreads();
    int idx = b * 256 + t;
    int di = (idx < NN) ? deg_in[idx] : 0;
    si[t] = di;
    __syncthreads();
    for (int off = 1; off < 256; off <<= 1) {
        int a = (t >= off) ? si[t - off] : 0;
        __syncthreads();
        si[t] += a;
        __syncthreads();
    }
    if (idx < NN) {
        rp_in[idx] = off_in + si[t] - di;   // exclusive
        float dif = rsqrtf((float)(di + 1));
        float dqf = rsqrtf((float)(deg_out[idx] + 1));
        dins[idx] = dif;
        douts[idx] = dqf;
        float4 x4 = ((const float4*)x)[idx];
        x4.x *= dqf; x4.y *= dqf; x4.z *= dqf; x4.w *= dqf;
        xs4[idx] = x4;
    }
    if (b == 0 && t == 0) rp_in[NN] = NE;
}

// ---------- K3: scatter edges into dst-CSR {src,dst}, permute ef, accumulate c ----------
__global__ __launch_bounds__(256) void k_scatter(const int* __restrict__ src,
                                                 const int* __restrict__ dst,
                                                 const float* __restrict__ ef,
                                                 const int* __restrict__ rp_in,
                                                 const float* __restrict__ dins,
                                                 int* __restrict__ cur_in,
                                                 int2* __restrict__ ndcsr,
                                                 float4* __restrict__ ef4,
                                                 float* __restrict__ c) {
    int e = blockIdx.x * 256 + threadIdx.x;
    if (e >= NE) return;
    int s = src[e], d = dst[e];
    int pi = rp_in[d] + atomicAdd(&cur_in[d], 1);
    ndcsr[pi] = make_int2(s, d);
    const float* er = ef + (size_t)e * 11;
    ef4[(size_t)pi * 3 + 0] = make_float4(er[0], er[1], er[2], er[3]);
    ef4[(size_t)pi * 3 + 1] = make_float4(er[4], er[5], er[6], er[7]);
    ef4[(size_t)pi * 3 + 2] = make_float4(er[8], er[9], er[10], 0.f);
    unsafeAtomicAdd(&c[s], dins[d]);   // native fp32 atomic (no CAS loop)
}

// ---------- K4: conv1 via CSR gather + fused 4->11 matvec/relu; h1s padded to 12 ----------
__global__ __launch_bounds__(256) void k_conv1g(const float4* __restrict__ xs4,
                                                const int2* __restrict__ ndcsr,
                                                const int* __restrict__ rp_in,
                                                const float* __restrict__ dins,
                                                const float* __restrict__ douts,
                                                const float* __restrict__ W1,
                                                const float* __restrict__ b1,
                                                float4* __restrict__ h1s4) {
    int n = blockIdx.x * 256 + threadIdx.x;
    if (n >= NN) return;
    float din  = dins[n];
    float dout = douts[n];
    float4 a = xs4[n];  // self-loop term, pre-scaled by dout_n
    int beg = rp_in[n], end = rp_in[n + 1];
    for (int p = beg; p < end; p++) {
        float4 xs = xs4[ndcsr[p].x];
        a.x += xs.x; a.y += xs.y; a.z += xs.z; a.w += xs.w;
    }
    float y[12];
    #pragma unroll
    for (int j = 0; j < 11; j++) {
        float t2 = a.x * W1[0 * 11 + j] + a.y * W1[1 * 11 + j] +
                   a.z * W1[2 * 11 + j] + a.w * W1[3 * 11 + j];
        y[j] = fmaxf(fmaf(t2, din, b1[j]), 0.f) * dout;
    }
    y[11] = 0.f;
    h1s4[(size_t)n * 3 + 0] = make_float4(y[0], y[1], y[2],  y[3]);
    h1s4[(size_t)n * 3 + 1] = make_float4(y[4], y[5], y[6],  y[7]);
    h1s4[(size_t)n * 3 + 2] = make_float4(y[8], y[9], y[10], y[11]);
}

// ---------- K5: conv2 — contiguous edge chunks, register acc + dst-change flush ----------
// tile rows are 12 floats; flushes use native LDS fp atomics; t_pad line-padded.
__global__ __launch_bounds__(256) void k_conv2f(const float4* __restrict__ h1s4,
                                                const float4* __restrict__ ef4,
                                                const int2* __restrict__ ndcsr,
                                                const int* __restrict__ rp_in,
                                                const float* __restrict__ c,
                                                const float* __restrict__ dins,
                                                const float* __restrict__ douts,
                                                const float* __restrict__ W2,
                                                const float* __restrict__ b2,
                                                float* __restrict__ t_pad) {
    __shared__ float tile[G2 * 12];
    __shared__ float din_sh[G2], w_sh[G2];
    int tid = threadIdx.x;
    int n0 = blockIdx.x * G2;
    int nend = (n0 + G2 < NN) ? n0 + G2 : NN;
    for (int i = tid; i < G2 * 12; i += 256) tile[i] = 0.f;
    if (tid < G2) {
        int n = n0 + tid;
        if (n < NN) {
            float din = dins[n];
            din_sh[tid] = din;
            w_sh[tid]   = (c[n] + din) * douts[n] * (1.0f / NN);  // +din = self loop
        } else { din_sh[tid] = 0.f; w_sh[tid] = 0.f; }
    }
    __syncthreads();
    // phase 1: contiguous chunk per thread; register-accumulate runs of equal dst
    int pbeg = rp_in[n0], pend = rp_in[nend];
    int range = pend - pbeg;
    int chunk = (range + 255) >> 8;
    int p0 = pbeg + tid * chunk;
    int p1 = p0 + chunk; if (p1 > pend) p1 = pend;
    float acc[11];
    int cur = -1;
    for (int p = p0; p < p1; p++) {
        int2 sd = ndcsr[p];
        if (sd.y != cur) {
            if (cur >= 0) {
                float* row = &tile[(cur - n0) * 12];
                #pragma unroll
                for (int j = 0; j < 11; j++) unsafeAtomicAdd(&row[j], acc[j]);
            }
            cur = sd.y;
            #pragma unroll
            for (int j = 0; j < 11; j++) acc[j] = 0.f;
        }
        float4 ha = h1s4[(size_t)sd.x * 3 + 0];
        float4 hb = h1s4[(size_t)sd.x * 3 + 1];
        float4 hc = h1s4[(size_t)sd.x * 3 + 2];
        float4 ea = ef4[(size_t)p * 3 + 0];
        float4 eb = ef4[(size_t)p * 3 + 1];
        float4 ec = ef4[(size_t)p * 3 + 2];
        acc[0]  = fmaf(ha.x, ea.x, acc[0]);
        acc[1]  = fmaf(ha.y, ea.y, acc[1]);
        acc[2]  = fmaf(ha.z, ea.z, acc[2]);
        acc[3]  = fmaf(ha.w, ea.w, acc[3]);
        acc[4]  = fmaf(hb.x, eb.x, acc[4]);
        acc[5]  = fmaf(hb.y, eb.y, acc[5]);
        acc[6]  = fmaf(hb.z, eb.z, acc[6]);
        acc[7]  = fmaf(hb.w, eb.w, acc[7]);
        acc[8]  = fmaf(hc.x, ec.x, acc[8]);
        acc[9]  = fmaf(hc.y, ec.y, acc[9]);
        acc[10] = fmaf(hc.w == 0.f ? hc.z : hc.z, ec.z, acc[10]);
    }
    if (cur >= 0) {
        float* row = &tile[(cur - n0) * 12];
        #pragma unroll
        for (int j = 0; j < 11; j++) unsafeAtomicAdd(&row[j], acc[j]);
    }
    __syncthreads();
    // phase 2: two channels per thread
    int ch0 = tid, ch1 = tid + 256;
    float w0[11], w1[11];
    #pragma unroll
    for (int j = 0; j < 11; j++) { w0[j] = W2[j * 512 + ch0]; w1[j] = W2[j * 512 + ch1]; }
    float b0 = b2[ch0], b1v = b2[ch1];
    float acc0 = 0.f, acc1 = 0.f;
    int cnt = nend - n0;
    for (int i = 0; i < cnt; i++) {
        const float4* trow = (const float4*)&tile[i * 12];
        float4 ta = trow[0], tb = trow[1], tc = trow[2];
        float din = din_sh[i], wn = w_sh[i];
        float dot0 = ta.x * w0[0] + ta.y * w0[1] + ta.z * w0[2] + ta.w * w0[3] +
                     tb.x * w0[4] + tb.y * w0[5] + tb.z * w0[6] + tb.w * w0[7] +
                     tc.x * w0[8] + tc.y * w0[9] + tc.z * w0[10];
        float dot1 = ta.x * w1[0] + ta.y * w1[1] + ta.z * w1[2] + ta.w * w1[3] +
                     tb.x * w1[4] + tb.y * w1[5] + tb.z * w1[6] + tb.w * w1[7] +
                     tc.x * w1[8] + tc.y * w1[9] + tc.z * w1[10];
        acc0 = fmaf(wn, fmaxf(fmaf(dot0, din, b0),  0.f), acc0);
        acc1 = fmaf(wn, fmaxf(fmaf(dot1, din, b1v), 0.f), acc1);
    }
    unsafeAtomicAdd(&t_pad[ch0 * 16], acc0);
    unsafeAtomicAdd(&t_pad[ch1 * 16], acc1);
}

// ---------- K6: g = t @ W3 + b3  (512x1024 matvec, k-split 32 ways, padded acc) ----------
__global__ __launch_bounds__(256) void k_g(const float* __restrict__ t_pad,
                                           const float* __restrict__ W3,
                                           const float* __restrict__ b3,
                                           float* __restrict__ g_pad) {
    int b = blockIdx.x;          // 128 = 4 oc x 32 kc
    int oc = b & 3, kc = b >> 2;
    int o = oc * 256 + threadIdx.x;
    int k0 = kc * 16;
    __shared__ float ts[16];
    if (threadIdx.x < 16) ts[threadIdx.x] = t_pad[(k0 + threadIdx.x) * 16];
    __syncthreads();
    float acc = (kc == 0) ? b3[o] : 0.f;
    #pragma unroll
    for (int k = 0; k < 16; k++) acc = fmaf(ts[k], W3[(size_t)(k0 + k) * 1024 + o], acc);
    unsafeAtomicAdd(&g_pad[o * 16], acc);
}

// ---------- K7: head layer-1 partial matvecs (bias/relu deferred, padded acc) ----------
__global__ __launch_bounds__(256) void k_heads1(const float* __restrict__ g_pad,
                                                const float* __restrict__ Wv1,
                                                const float* __restrict__ Wa1,
                                                float* __restrict__ hv_pad,
                                                float* __restrict__ ha_pad) {
    int b = blockIdx.x;
    int oc = b >> 5, kc = b & 31;
    int idx = oc * 256 + threadIdx.x;  // 0..4095
    int k0 = kc * 32;
    __shared__ float gs[32];
    if (threadIdx.x < 32) gs[threadIdx.x] = g_pad[(k0 + threadIdx.x) * 16];
    __syncthreads();
    const float* W; float* outp; int o;
    if (idx < 2048) { W = Wv1; outp = hv_pad; o = idx; }
    else            { W = Wa1; outp = ha_pad; o = idx - 2048; }
    float acc = 0.f;
    #pragma unroll 8
    for (int k = 0; k < 32; k++) acc = fmaf(gs[k], W[(size_t)(k0 + k) * 2048 + o], acc);
    unsafeAtomicAdd(&outp[o * 16], acc);
}

// ---------- K8: head layer-2: a partials (256 blocks, padded acc) + v (1 block) ----------
__global__ __launch_bounds__(256) void k_heads2(const float* __restrict__ hv_pad,
                                                const float* __restrict__ bv1,
                                                const float* __restrict__ ha_pad,
                                                const float* __restrict__ ba1,
                                                const float* __restrict__ Wv2,
                                                const float* __restrict__ bv2,
                                                const float* __restrict__ Wa2,
                                                float* __restrict__ a_pad,
                                                float* __restrict__ v) {
    int b = blockIdx.x;
    int tid = threadIdx.x;
    if (b < 256) {
        int oc = b >> 6, kc = b & 63;   // oc 0..3, kc 0..63
        int k0 = kc * 32;
        __shared__ float hs[32];
        if (tid < 32) hs[tid] = fmaxf(ha_pad[(k0 + tid) * 16] + ba1[k0 + tid], 0.f);
        __syncthreads();
        int o = oc * 256 + tid;  // 0..1023
        if (o < 1000) {
            float acc = 0.f;
            #pragma unroll 8
            for (int k = 0; k < 32; k++)
                acc = fmaf(hs[k], Wa2[(size_t)(k0 + k) * 1000 + o], acc);
            unsafeAtomicAdd(&a_pad[o * 16], acc);
        }
    } else {
        __shared__ float red[256];
        float acc = 0.f;
        for (int k = tid; k < 2048; k += 256)
            acc = fmaf(fmaxf(hv_pad[k * 16] + bv1[k], 0.f), Wv2[k], acc);
        red[tid] = acc;
        __syncthreads();
        for (int s = 128; s >= 1; s >>= 1) {
            if (tid < s) red[tid] += red[tid + s];
            __syncthreads();
        }
        if (tid == 0) *v = red[0] + bv2[0];
    }
}

// ---------- K9: final: out = v + (a - mean(a)) ----------
__global__ __launch_bounds__(1024) void k_final(const float* __restrict__ a_pad,
                                                const float* __restrict__ ba2,
                                                const float* __restrict__ vptr,
                                                float* __restrict__ out) {
    __shared__ float red[1024];
    int tid = threadIdx.x;
    float ai = (tid < 1000) ? a_pad[tid * 16] + ba2[tid] : 0.f;
    red[tid] = ai;
    __syncthreads();
    for (int s = 512; s >= 1; s >>= 1) {
        if (tid < s) red[tid] += red[tid + s];
        __syncthreads();
    }
    float amean = red[0] * (1.0f / 1000.0f);
    if (tid < 1000) out[tid] = vptr[0] + ai - amean;
}

extern "C" void kernel_launch(void* const* d_in, const int* in_sizes, int n_in,
                              void* d_out, int out_size, void* d_ws, size_t ws_size,
                              hipStream_t stream) {
    const float* x   = (const float*)d_in[0];
    const float* ef  = (const float*)d_in[1];
    const float* W1  = (const float*)d_in[2];
    const float* b1  = (const float*)d_in[3];
    const float* W2  = (const float*)d_in[4];
    const float* b2  = (const float*)d_in[5];
    const float* W3  = (const float*)d_in[6];
    const float* b3  = (const float*)d_in[7];
    const float* Wv1 = (const float*)d_in[8];
    const float* bv1 = (const float*)d_in[9];
    const float* Wv2 = (const float*)d_in[10];
    const float* bv2 = (const float*)d_in[11];
    const float* Wa1 = (const float*)d_in[12];
    const float* ba1 = (const float*)d_in[13];
    const float* Wa2 = (const float*)d_in[14];
    const float* ba2 = (const float*)d_in[15];
    const int*   src = (const int*)d_in[16];
    const int*   dst = (const int*)d_in[17];
    float* out = (float*)d_out;

    char* ws = (char*)d_ws;
    size_t off = 0;
    auto alloc = [&](size_t bytes) -> void* {
        void* p = ws + off;
        off = (off + bytes + 255) & ~(size_t)255;
        return p;
    };
    // --- zeroed region (accumulators) ---
    int*   deg_out = (int*)  alloc(NN * 4);
    int*   deg_in  = (int*)  alloc(NN * 4);
    int*   cur_in  = (int*)  alloc(NN * 4);
    float* c       = (float*)alloc(NN * 4);
    float* t_pad   = (float*)alloc(512 * 16 * 4);
    float* g_pad   = (float*)alloc(1024 * 16 * 4);
    float* hv_pad  = (float*)alloc(2048 * 16 * 4);
    float* ha_pad  = (float*)alloc(2048 * 16 * 4);
    float* a_pad   = (float*)alloc(1024 * 16 * 4);
    size_t zero_bytes = off;
    // --- non-zeroed scratch ---
    int*    bsum     = (int*)   alloc(NB * 4);
    int*    rp_in    = (int*)   alloc((NN + 1) * 4);
    float*  dins     = (float*) alloc(NN * 4);
    float*  douts    = (float*) alloc(NN * 4);
    float4* xs4      = (float4*)alloc((size_t)NN * 16);
    int2*   ndcsr    = (int2*)  alloc((size_t)NE * 8);
    float4* ef4      = (float4*)alloc((size_t)NE * 48);
    float4* h1s4     = (float4*)alloc((size_t)NN * 48);
    float*  v        = (float*) alloc(256);

    hipMemsetAsync(d_ws, 0, zero_bytes, stream);

    k_deg<<<(NE + 255) / 256, 256, 0, stream>>>(src, dst, deg_out, deg_in);
    k_bsum<<<NB, 256, 0, stream>>>(deg_in, bsum);
    k_rowptr<<<NB, 256, 0, stream>>>(deg_in, deg_out, bsum, x, rp_in, dins, douts, xs4);
    k_scatter<<<(NE + 255) / 256, 256, 0, stream>>>(src, dst, ef, rp_in, dins,
                                                    cur_in, ndcsr, ef4, c);
    k_conv1g<<<(NN + 255) / 256, 256, 0, stream>>>(xs4, ndcsr, rp_in, dins, douts,
                                                   W1, b1, h1s4);
    k_conv2f<<<NT2, 256, 0, stream>>>(h1s4, ef4, ndcsr, rp_in, c,
                                      dins, douts, W2, b2, t_pad);
    k_g<<<128, 256, 0, stream>>>(t_pad, W3, b3, g_pad);
    k_heads1<<<512, 256, 0, stream>>>(g_pad, Wv1, Wa1, hv_pad, ha_pad);
    k_heads2<<<257, 256, 0, stream>>>(hv_pad, bv1, ha_pad, ba1, Wv2, bv2, Wa2, a_pad, v);
    k_final<<<1, 1024, 0, stream>>>(a_pad, ba2, v, out);
}